// Round 8
// baseline (97.966 us; speedup 1.0000x reference)
//
#include <hip/hip_runtime.h>

typedef unsigned short u16;
typedef unsigned int u32;
typedef __attribute__((ext_vector_type(8))) __bf16 bf16x8;
typedef __attribute__((ext_vector_type(4))) __bf16 bf16x4;
typedef __attribute__((ext_vector_type(4))) float f32x4;

#define S_LEN 169
#define SP 192
#define GREP 3   // measurement repeat for g_kernel (idempotent)

// ---------------- workspace layout (bytes)
#define W2T_WS 0                          // bf16 [256][192] = 98304
#define WPK_WS 98304                      // bf16 frag-packed [3][1024][16B] = 49152
#define KE_WS  147456                     // f32  [256][176][16] = 2883584
#define KV_WS  (KE_WS + 2883584)          // bf16 [256][176][16] = 1441792
#define SG_WS  (KV_WS + 1441792)          // f32  [256][176][16] = 2883584

// ---------------- G kernel LDS (40 KB -> 4 blocks/CU exactly)
#define F32A 0
#define F32B 16384
#define BFT  32768
#define G_LDS 40960

// ---------------- S kernel LDS
#define SKE  0        // [176][16] f32 (t<169 valid)
#define SKV  11264    // [169][16] bf16
#define SG2  16896    // [176][16] f32
#define SKVT 28160    // [16][192] bf16 swz
#define SRB  34304    // [256][40] bf16
#define SSS  54784    // [16][16] f32
#define SOW  55808    // [64][40] bf16
#define S_LDS 60928

// ---------------- K0: blocks 0..191 compute w2t; blocks 192..194 pack weights
__global__ __launch_bounds__(1024) void k0_kernel(
    const float* __restrict__ time_w,
    const float* __restrict__ time_alpha,
    const float* __restrict__ time_beta,
    const float* __restrict__ key_w,
    const float* __restrict__ value_w,
    const float* __restrict__ recep_w,
    char* __restrict__ ws)
{
    __bf16* w2t = (__bf16*)(ws + W2T_WS);
    const int blk = blockIdx.x;
    if (blk >= 192) {
        const int m = blk - 192;
        const float* wmat = (m == 0) ? key_w : (m == 1) ? value_w : recep_w;
        const int g = threadIdx.x;
        if (g < 1024) {
            const float* src = wmat + g * 8;
            float4 f0 = *(const float4*)src;
            float4 f1 = *(const float4*)(src + 4);
            bf16x8 p;
            p[0]=(__bf16)f0.x; p[1]=(__bf16)f0.y; p[2]=(__bf16)f0.z; p[3]=(__bf16)f0.w;
            p[4]=(__bf16)f1.x; p[5]=(__bf16)f1.y; p[6]=(__bf16)f1.z; p[7]=(__bf16)f1.w;
            int hs = g >> 6, rem = g & 63, ks = rem >> 2, q = rem & 3;
            int fid = ks * 64 + q * 16 + hs;
            *(bf16x8*)(ws + WPK_WS + m * 16384 + fid * 16) = p;
        }
        return;
    }
    __shared__ float tw[256];
    __shared__ float al[256];
    __shared__ float part[4][256];
    const int s = blk;
    const int t = threadIdx.x & 255;
    const int p = threadIdx.x >> 8;
    if (s >= S_LEN) {
        if (p == 0) w2t[t * SP + s] = (__bf16)0.f;
        return;
    }
    if (p == 0) { tw[t] = time_w[s * 256 + t]; al[t] = time_alpha[s * 256 + t]; }
    __syncthreads();
    const int u0 = p << 6;
    const int u1 = (u0 + 64 < t + 1) ? (u0 + 64) : (t + 1);
    float acc = 0.f;
    for (int u = u0; u < u1; ++u)
        acc = fmaf(tw[255 + u - t], al[u], acc);
    part[p][t] = acc;
    __syncthreads();
    if (p == 0)
        w2t[t * SP + s] = (__bf16)(time_beta[s * 256 + t] *
                                   (part[0][t] + part[1][t] + part[2][t] + part[3][t]));
}

// ---------------- G: GEMM1 + pointwise. 768 blocks = (b, slab of 64 t-rows), 256 thr.
// Race-fixed counted-vmcnt schedule; 40 KB LDS -> 4 blocks/CU. GREP internal repeats.
__global__ __launch_bounds__(256, 4) void g_kernel(
    const float* __restrict__ x,
    const float* __restrict__ key_b,
    const float* __restrict__ value_b,
    const float* __restrict__ recep_b,
    char* __restrict__ ws)
{
    __shared__ __align__(16) char smem[G_LDS];
    const int tid  = threadIdx.x;
    const int lane = tid & 63;
    const int wid  = tid >> 6;       // waves 0-2 = matrices k/v/r, wave 3 = stage helper
    const int q    = lane >> 4;
    const int hs   = lane & 15;
    const int blk  = blockIdx.x;
    const int b    = blk / 3;
    const int slab = blk - b * 3;
    const int t0   = slab * 64;
    const int rquad = wid * 4 + q;
    const float* xb = x + (size_t)b * (S_LEN * 512);

    // B-fragments from pre-packed ws: 16 coalesced 1 KB wave-loads, L2-hot
    bf16x8 bfrag[16];
    if (wid < 3) {
        #pragma unroll
        for (int ks = 0; ks < 16; ++ks)
            bfrag[ks] = *(const bf16x8*)(ws + WPK_WS + wid * 16384 + (ks * 64 + lane) * 16);
    }
    const float* bv = (wid == 0) ? key_b : (wid == 1) ? value_b : recep_b;
    const float bias = (wid < 3) ? bv[hs] : 0.f;

    float* keg = (float*)(ws + KE_WS);
    __bf16* kvg = (__bf16*)(ws + KV_WS);
    float* sgg = (float*)(ws + SG_WS);

    f32x4 acc[4];

    // async stage of chunk c (64 rows x 64 f32 cols): 4 gl_lds per thread, linear dest
    auto issue = [&](int c, u32 fbuf) {
        const int row_base = (c < 4) ? (t0 - 1) : t0;   // channel shift on first 256 cols
        #pragma unroll
        for (int it = 0; it < 4; ++it) {
            int row = it * 16 + rquad;
            int rg  = row_base + row;
            int grc = rg < 0 ? 0 : (rg > S_LEN - 1 ? S_LEN - 1 : rg);  // clamp: unconditional load
            const float* src = xb + (size_t)grc * 512 + c * 64 + hs * 4;
            void* ldst = (void*)(smem + fbuf + it * 4096 + wid * 1024);  // wave-uniform base
            __builtin_amdgcn_global_load_lds((const __attribute__((address_space(1))) void*)src,
                                             (__attribute__((address_space(3))) void*)ldst,
                                             16, 0, 0);
        }
    };

    // f32 LDS -> cvt -> swizzled bf16 tile (invalid rows -> 0)
    auto cvt = [&](int c, u32 fbuf) {
        const int row_base = (c < 4) ? (t0 - 1) : t0;
        #pragma unroll
        for (int it = 0; it < 4; ++it) {
            int u   = it * 256 + tid;
            int row = u >> 4;
            f32x4 f = *(const f32x4*)(smem + fbuf + (u32)u * 16);
            int rg = row_base + row;
            if ((unsigned)rg >= (unsigned)S_LEN) f = (f32x4){0.f, 0.f, 0.f, 0.f};
            bf16x4 p;
            p[0] = (__bf16)f[0]; p[1] = (__bf16)f[1]; p[2] = (__bf16)f[2]; p[3] = (__bf16)f[3];
            u32 off = (u32)row * 128 + ((((u32)u & 15u) * 8u) ^ (((u32)row & 7u) << 4));
            *(bf16x4*)(smem + BFT + off) = p;
        }
    };

    auto domfma = [&](int c) {
        if (wid < 3) {
            #pragma unroll
            for (int s2 = 0; s2 < 2; ++s2) {
                #pragma unroll
                for (int mt = 0; mt < 4; ++mt) {
                    int r = mt * 16 + hs;
                    u32 off = (u32)r * 128 + (((u32)(64 * s2 + 16 * q)) ^ (((u32)(r & 7)) << 4));
                    bf16x8 a = *(const bf16x8*)(smem + BFT + off);
                    acc[mt] = __builtin_amdgcn_mfma_f32_16x16x32_bf16(a, bfrag[c * 2 + s2], acc[mt], 0, 0, 0);
                }
            }
        }
    };

#define BAR1() asm volatile("s_waitcnt lgkmcnt(0)\n\ts_barrier" ::: "memory")
#define BAR2(VM) asm volatile("s_waitcnt vmcnt(" #VM ") lgkmcnt(0)\n\ts_barrier" ::: "memory")

    for (int rep = 0; rep < GREP; ++rep) {
        #pragma unroll
        for (int mt = 0; mt < 4; ++mt) acc[mt] = (f32x4){0.f, 0.f, 0.f, 0.f};

        issue(0, F32A);
        issue(1, F32B);
        BAR2(4);                                        // own c0 landed; barrier joins all
        cvt(0, F32A); BAR1(); issue(2, F32A); domfma(0); BAR2(4);
        cvt(1, F32B); BAR1(); issue(3, F32B); domfma(1); BAR2(4);
        cvt(2, F32A); BAR1(); issue(4, F32A); domfma(2); BAR2(4);
        cvt(3, F32B); BAR1(); issue(5, F32B); domfma(3); BAR2(4);
        cvt(4, F32A); BAR1(); issue(6, F32A); domfma(4); BAR2(4);
        cvt(5, F32B); BAR1(); issue(7, F32B); domfma(5); BAR2(4);
        cvt(6, F32A); BAR1();                 domfma(6); BAR2(0);
        cvt(7, F32B); BAR1();                 domfma(7);

        // epilogue: raw acc (+bias) -> LDS [3][64][16] f32 (overlays F32A), combine -> ws
        float* raw = (float*)(smem + F32A);
        if (wid < 3) {
            #pragma unroll
            for (int mt = 0; mt < 4; ++mt) {
                #pragma unroll
                for (int rg = 0; rg < 4; ++rg) {
                    int tl = mt * 16 + q * 4 + rg;
                    raw[wid * 1024 + tl * 16 + hs] = acc[mt][rg] + bias;
                }
            }
        }
        __syncthreads();
        #pragma unroll
        for (int it = 0; it < 4; ++it) {
            int i  = it * 256 + tid;
            int tl = i >> 4, h = i & 15;
            int t  = t0 + tl;
            if (t < S_LEN) {
                float kk = fminf(fmaxf(raw[i], -60.f), 30.f);
                float ke = __expf(kk);
                size_t o = ((size_t)b * 176 + t) * 16 + h;
                keg[o] = ke;
                kvg[o] = (__bf16)(ke * raw[1024 + i]);
                sgg[o] = 1.f / (1.f + __expf(-raw[2048 + i]));
            }
        }
        __syncthreads();   // raw reads done before next rep's gl_lds overwrite F32A
    }
#undef BAR1
#undef BAR2
}

// ---------------- kernel S: scan + wkv + out-proj. 256 blocks (one per b)
__global__ __launch_bounds__(256) void scan_kernel(
    const char* __restrict__ wsr,
    const float* __restrict__ out_w, const float* __restrict__ out_b,
    const float* __restrict__ gamma,
    float* __restrict__ out)
{
    __shared__ __align__(16) char smem[S_LDS];
    const int tid  = threadIdx.x;
    const int lane = tid & 63;
    const int wid  = tid >> 6;
    const int q    = lane >> 4;
    const int hs   = lane & 15;
    const int b    = blockIdx.x;
    const __bf16* w2t = (const __bf16*)(wsr + W2T_WS);
    const float4* keb = (const float4*)(wsr + KE_WS + (size_t)b * 11264);
    const float4* kvb = (const float4*)(wsr + KV_WS + (size_t)b * 5632);
    const float4* sgb = (const float4*)(wsr + SG_WS + (size_t)b * 11264);

    #pragma unroll
    for (int it = 0; it < 3; ++it) {
        int i = tid + (it << 8);
        if (i < 676) {
            ((float4*)(smem + SKE))[i] = keb[i];
            ((float4*)(smem + SG2))[i] = sgb[i];
        }
        if (i < 338) ((float4*)(smem + SKV))[i] = kvb[i];
    }
    for (int i = tid; i < 2560; i += 256) {
        int o = i / 40, c = i - o * 40;
        ((__bf16*)(smem + SOW))[i] = (c < 16) ? (__bf16)out_w[o * 16 + c] : (__bf16)0.f;
    }
    for (int i = tid; i < 4096; i += 256) {
        int row = i >> 4, c = 16 + (i & 15);
        ((__bf16*)(smem + SRB))[row * 40 + c] = (__bf16)0.f;
    }
    for (int i = tid; i < 368; i += 256) {
        int h2 = i & 15; int t = S_LEN + (i >> 4);
        u32 off = ((u32)(h2 * 384 + t * 2)) ^ (((u32)(h2 & 7)) << 4);
        *(__bf16*)(smem + SKVT + off) = (__bf16)0.f;
    }
    __syncthreads();

    float* KE = (float*)(smem + SKE);
    float* GG = (float*)(smem + SG2);
    float* SEG = (float*)(smem + SSS);
    const int h  = tid & 15;
    const int sg = tid >> 4;
    const int ts = sg * 11;
    const int te = (ts + 11 < S_LEN) ? ts + 11 : S_LEN;
    {
        float ssum = 0.f;
        for (int t = ts; t < te; ++t) ssum += KE[t * 16 + h];
        SEG[sg * 16 + h] = ssum;
    }
    __syncthreads();
    {
        float run = 0.f;
        for (int s2 = 0; s2 < sg; ++s2) run += SEG[s2 * 16 + h];   // broadcast reads
        for (int t = ts; t < te; ++t) {
            run += KE[t * 16 + h];                                 // inclusive cumsum = denom
            u32 off = ((u32)(h * 384 + t * 2)) ^ (((u32)(h & 7)) << 4);
            *(__bf16*)(smem + SKVT + off) = ((const __bf16*)(smem + SKV))[t * 16 + h];
            GG[t * 16 + h] = GG[t * 16 + h] / run;                 // sigmoid/denom
        }
    }
    __syncthreads();

    // wkv: [256 t] x [192 s] @ [192 s][16 c]; A-frags from global w2t (L2-hot)
    f32x4 wa[4];
    #pragma unroll
    for (int mi = 0; mi < 4; ++mi) wa[mi] = (f32x4){0.f,0.f,0.f,0.f};
    #pragma unroll
    for (int s0 = 0; s0 < SP; s0 += 32) {
        int scol = s0 + (q << 3);
        u32 boff = ((u32)(hs * 384 + scol * 2)) ^ (((u32)(hs & 7)) << 4);
        bf16x8 bfr = *(const bf16x8*)(smem + SKVT + boff);
        #pragma unroll
        for (int mi = 0; mi < 4; ++mi) {
            int row = (wid + (mi << 2)) * 16 + hs;
            bf16x8 afr = *(const bf16x8*)(w2t + row * SP + scol);
            wa[mi] = __builtin_amdgcn_mfma_f32_16x16x32_bf16(afr, bfr, wa[mi], 0,0,0);
        }
    }
    #pragma unroll
    for (int mi = 0; mi < 4; ++mi) {
        int tb = (wid + (mi << 2)) * 16 + (q << 2);
        #pragma unroll
        for (int rg = 0; rg < 4; ++rg) {
            int t = tb + rg;
            float fac = (t < S_LEN) ? GG[t * 16 + hs] : 0.5f;
            ((__bf16*)(smem + SRB))[t * 40 + hs] = (__bf16)(wa[mi][rg] * fac);
        }
    }
    __syncthreads();

    float obv[4];
    #pragma unroll
    for (int nt = 0; nt < 4; ++nt) obv[nt] = out_b[nt * 16 + hs];
    #pragma unroll
    for (int mi = 0; mi < 4; ++mi) {
        int mt = wid + (mi << 2);
        int arow = mt * 16 + hs;
        bf16x8 afr = *(const bf16x8*)(smem + SRB + (u32)(arow * 80 + (q << 4)));
        float gm[4];
        #pragma unroll
        for (int rg = 0; rg < 4; ++rg) gm[rg] = gamma[mt * 16 + (q << 2) + rg];
        #pragma unroll
        for (int nt = 0; nt < 4; ++nt) {
            int orow = nt * 16 + hs;
            bf16x8 bfr = *(const bf16x8*)(smem + SOW + (u32)(orow * 80 + (q << 4)));
            f32x4 zc = (f32x4){0.f,0.f,0.f,0.f};
            f32x4 d = __builtin_amdgcn_mfma_f32_16x16x32_bf16(afr, bfr, zc, 0,0,0);
            #pragma unroll
            for (int rg = 0; rg < 4; ++rg) {
                int t = mt * 16 + (q << 2) + rg;
                out[(size_t)b * 16384 + (size_t)t * 64 + nt * 16 + hs] = (d[rg] + obv[nt]) * gm[rg];
            }
        }
    }
}

extern "C" void kernel_launch(void* const* d_in, const int* in_sizes, int n_in,
                              void* d_out, int out_size, void* d_ws, size_t ws_size,
                              hipStream_t stream) {
    const float* x          = (const float*)d_in[0];
    const float* time_w     = (const float*)d_in[1];
    const float* time_alpha = (const float*)d_in[2];
    const float* time_beta  = (const float*)d_in[3];
    const float* time_gamma = (const float*)d_in[4];
    const float* key_w      = (const float*)d_in[5];
    const float* key_b      = (const float*)d_in[6];
    const float* value_w    = (const float*)d_in[7];
    const float* value_b    = (const float*)d_in[8];
    const float* recep_w    = (const float*)d_in[9];
    const float* recep_b    = (const float*)d_in[10];
    const float* out_w      = (const float*)d_in[11];
    const float* out_b      = (const float*)d_in[12];
    char* ws = (char*)d_ws;

    k0_kernel<<<195, 1024, 0, stream>>>(time_w, time_alpha, time_beta,
                                        key_w, value_w, recep_w, ws);
    g_kernel<<<768, 256, 0, stream>>>(x, key_b, value_b, recep_b, ws);
    scan_kernel<<<256, 256, 0, stream>>>(ws, out_w, out_b, time_gamma, (float*)d_out);
}

// Round 9
// 41.886 us; speedup vs baseline: 2.3389x; 2.3389x over previous
//
#include <hip/hip_runtime.h>

typedef unsigned short u16;
typedef unsigned int u32;
typedef __attribute__((ext_vector_type(8))) __bf16 bf16x8;
typedef __attribute__((ext_vector_type(4))) __bf16 bf16x4;
typedef __attribute__((ext_vector_type(4))) float f32x4;

#define S_LEN 169
#define SP 192

// ---------------- workspace layout (bytes)
#define W2T_WS 0                          // bf16 [256][192] = 98304
#define WPK_WS 98304                      // bf16 frag-packed [3][1024][16B] = 49152
#define KE_WS  147456                     // f32  [256][176][16] = 2883584
#define KV_WS  (KE_WS + 2883584)          // bf16 [256][176][16] = 1441792
#define SG_WS  (KV_WS + 1441792)          // f32  [256][176][16] = 2883584

// ---------------- S kernel LDS
#define SKE  0        // [176][16] f32 (t<169 valid)
#define SKV  11264    // [169][16] bf16
#define SG2  16896    // [176][16] f32
#define SKVT 28160    // [16][192] bf16 swz
#define SRB  34304    // [256][40] bf16
#define SSS  54784    // [16][16] f32
#define SOW  55808    // [64][40] bf16
#define S_LDS 60928

// ---------------- K0: blocks 0..191 compute w2t; blocks 192..194 pack weights
__global__ __launch_bounds__(1024) void k0_kernel(
    const float* __restrict__ time_w,
    const float* __restrict__ time_alpha,
    const float* __restrict__ time_beta,
    const float* __restrict__ key_w,
    const float* __restrict__ value_w,
    const float* __restrict__ recep_w,
    char* __restrict__ ws)
{
    __bf16* w2t = (__bf16*)(ws + W2T_WS);
    const int blk = blockIdx.x;
    if (blk >= 192) {
        const int m = blk - 192;
        const float* wmat = (m == 0) ? key_w : (m == 1) ? value_w : recep_w;
        const int g = threadIdx.x;
        if (g < 1024) {
            const float* src = wmat + g * 8;
            float4 f0 = *(const float4*)src;
            float4 f1 = *(const float4*)(src + 4);
            bf16x8 p;
            p[0]=(__bf16)f0.x; p[1]=(__bf16)f0.y; p[2]=(__bf16)f0.z; p[3]=(__bf16)f0.w;
            p[4]=(__bf16)f1.x; p[5]=(__bf16)f1.y; p[6]=(__bf16)f1.z; p[7]=(__bf16)f1.w;
            int hs = g >> 6, rem = g & 63, ks = rem >> 2, q = rem & 3;
            int fid = ks * 64 + q * 16 + hs;
            *(bf16x8*)(ws + WPK_WS + m * 16384 + fid * 16) = p;
        }
        return;
    }
    __shared__ float tw[256];
    __shared__ float al[256];
    __shared__ float part[4][256];
    const int s = blk;
    const int t = threadIdx.x & 255;
    const int p = threadIdx.x >> 8;
    if (s >= S_LEN) {
        if (p == 0) w2t[t * SP + s] = (__bf16)0.f;
        return;
    }
    if (p == 0) { tw[t] = time_w[s * 256 + t]; al[t] = time_alpha[s * 256 + t]; }
    __syncthreads();
    const int u0 = p << 6;
    const int u1 = (u0 + 64 < t + 1) ? (u0 + 64) : (t + 1);
    float acc = 0.f;
    for (int u = u0; u < u1; ++u)
        acc = fmaf(tw[255 + u - t], al[u], acc);
    part[p][t] = acc;
    __syncthreads();
    if (p == 0)
        w2t[t * SP + s] = (__bf16)(time_beta[s * 256 + t] *
                                   (part[0][t] + part[1][t] + part[2][t] + part[3][t]));
}

// ---------------- G: GEMM1 + pointwise. 2816 blocks = (b, slab of 16 t-rows), 192 thr.
// One-shot: contiguous stage -> 1 barrier -> 16 MFMA/wave -> epilogue. No phase loop.
__global__ __launch_bounds__(192) void g_kernel(
    const float* __restrict__ x,
    const float* __restrict__ key_b,
    const float* __restrict__ value_b,
    const float* __restrict__ recep_b,
    char* __restrict__ ws)
{
    __shared__ __align__(16) char smem[17408];   // bf16 [17][512] swizzled
    const int tid  = threadIdx.x;
    const int lane = tid & 63;
    const int wid  = tid >> 6;       // 0..2 -> matrices k/v/r
    const int q    = lane >> 4;
    const int hs   = lane & 15;
    const int blk  = blockIdx.x;
    const int b    = blk / 11;
    const int slab = blk - b * 11;
    const int t0   = slab * 16;
    const float* xb = x + (size_t)b * (S_LEN * 512);

    // B-fragments from pre-packed ws: 16 contiguous 1 KB wave-loads, L2-hot
    bf16x8 bfrag[16];
    #pragma unroll
    for (int ks = 0; ks < 16; ++ks)
        bfrag[ks] = *(const bf16x8*)(ws + WPK_WS + wid * 16384 + (ks * 64 + lane) * 16);
    const float* bv = (wid == 0) ? key_b : (wid == 1) ? value_b : recep_b;
    const float bias = bv[hs];

    // stage rows t0-1 .. t0+15 (17 rows x 512 f32 = one contiguous 34 KB sweep)
    float4 st[12];
    int    sv[12];
    #pragma unroll
    for (int it = 0; it < 12; ++it) {
        int idx = tid + it * 192; if (idx > 2175) idx = 2175;   // 17*128 float4s
        int row = idx >> 7, c4 = idx & 127;
        int g   = t0 - 1 + row;
        sv[it]  = ((unsigned)g < (unsigned)S_LEN) ? 1 : 0;
        int gc  = g < 0 ? 0 : (g > S_LEN - 1 ? S_LEN - 1 : g);
        st[it]  = *(const float4*)(xb + (size_t)gc * 512 + c4 * 4);
    }
    #pragma unroll
    for (int it = 0; it < 12; ++it) {
        int idx = tid + it * 192; if (idx > 2175) idx = 2175;
        int row = idx >> 7, c4 = idx & 127;
        float4 f = st[it];
        if (!sv[it]) f = (float4){0.f, 0.f, 0.f, 0.f};
        bf16x4 p;
        p[0] = (__bf16)f.x; p[1] = (__bf16)f.y; p[2] = (__bf16)f.z; p[3] = (__bf16)f.w;
        u32 off = (u32)row * 1024 + ((((u32)c4) * 8u) ^ (((u32)(row & 7)) << 4));
        *(bf16x4*)(smem + off) = p;
    }
    __syncthreads();

    // MFMA: A[t0+hs][k] from LDS (shift rows: ks<8 -> staged row hs, else hs+1)
    f32x4 acc = (f32x4){0.f, 0.f, 0.f, 0.f};
    #pragma unroll
    for (int ks = 0; ks < 16; ++ks) {
        int r = hs + ((ks < 8) ? 0 : 1);
        u32 off = (u32)r * 1024 + (((u32)(ks * 64 + q * 16)) ^ (((u32)(r & 7)) << 4));
        bf16x8 a = *(const bf16x8*)(smem + off);
        acc = __builtin_amdgcn_mfma_f32_16x16x32_bf16(a, bfrag[ks], acc, 0, 0, 0);
    }
    __syncthreads();   // staging reads done; reuse LDS for raw exchange

    // epilogue: raw (+bias) -> LDS [3][16][16] f32, barrier, combine -> ws
    float* raw = (float*)smem;
    #pragma unroll
    for (int rg = 0; rg < 4; ++rg)
        raw[wid * 256 + (q * 4 + rg) * 16 + hs] = acc[rg] + bias;
    __syncthreads();

    float* keg = (float*)(ws + KE_WS);
    __bf16* kvg = (__bf16*)(ws + KV_WS);
    float* sgg = (float*)(ws + SG_WS);
    for (int i = tid; i < 256; i += 192) {
        int tl = i >> 4, h = i & 15;
        int t  = t0 + tl;
        if (t < S_LEN) {
            float kk = fminf(fmaxf(raw[i], -60.f), 30.f);
            float ke = __expf(kk);
            size_t o = ((size_t)b * 176 + t) * 16 + h;
            keg[o] = ke;
            kvg[o] = (__bf16)(ke * raw[256 + i]);
            sgg[o] = 1.f / (1.f + __expf(-raw[512 + i]));
        }
    }
}

// ---------------- kernel S: scan + wkv + out-proj. 256 blocks (one per b)
__global__ __launch_bounds__(256) void scan_kernel(
    const char* __restrict__ wsr,
    const float* __restrict__ out_w, const float* __restrict__ out_b,
    const float* __restrict__ gamma,
    float* __restrict__ out)
{
    __shared__ __align__(16) char smem[S_LDS];
    const int tid  = threadIdx.x;
    const int lane = tid & 63;
    const int wid  = tid >> 6;
    const int q    = lane >> 4;
    const int hs   = lane & 15;
    const int b    = blockIdx.x;
    const __bf16* w2t = (const __bf16*)(wsr + W2T_WS);
    const float4* keb = (const float4*)(wsr + KE_WS + (size_t)b * 11264);
    const float4* kvb = (const float4*)(wsr + KV_WS + (size_t)b * 5632);
    const float4* sgb = (const float4*)(wsr + SG_WS + (size_t)b * 11264);

    #pragma unroll
    for (int it = 0; it < 3; ++it) {
        int i = tid + (it << 8);
        if (i < 676) {
            ((float4*)(smem + SKE))[i] = keb[i];
            ((float4*)(smem + SG2))[i] = sgb[i];
        }
        if (i < 338) ((float4*)(smem + SKV))[i] = kvb[i];
    }
    for (int i = tid; i < 2560; i += 256) {
        int o = i / 40, c = i - o * 40;
        ((__bf16*)(smem + SOW))[i] = (c < 16) ? (__bf16)out_w[o * 16 + c] : (__bf16)0.f;
    }
    for (int i = tid; i < 4096; i += 256) {
        int row = i >> 4, c = 16 + (i & 15);
        ((__bf16*)(smem + SRB))[row * 40 + c] = (__bf16)0.f;
    }
    for (int i = tid; i < 368; i += 256) {
        int h2 = i & 15; int t = S_LEN + (i >> 4);
        u32 off = ((u32)(h2 * 384 + t * 2)) ^ (((u32)(h2 & 7)) << 4);
        *(__bf16*)(smem + SKVT + off) = (__bf16)0.f;
    }
    __syncthreads();

    float* KE = (float*)(smem + SKE);
    float* GG = (float*)(smem + SG2);
    float* SEG = (float*)(smem + SSS);
    const int h  = tid & 15;
    const int sg = tid >> 4;
    const int ts = sg * 11;
    const int te = (ts + 11 < S_LEN) ? ts + 11 : S_LEN;
    {
        float ssum = 0.f;
        for (int t = ts; t < te; ++t) ssum += KE[t * 16 + h];
        SEG[sg * 16 + h] = ssum;
    }
    __syncthreads();
    {
        float run = 0.f;
        for (int s2 = 0; s2 < sg; ++s2) run += SEG[s2 * 16 + h];   // broadcast reads
        for (int t = ts; t < te; ++t) {
            run += KE[t * 16 + h];                                 // inclusive cumsum = denom
            u32 off = ((u32)(h * 384 + t * 2)) ^ (((u32)(h & 7)) << 4);
            *(__bf16*)(smem + SKVT + off) = ((const __bf16*)(smem + SKV))[t * 16 + h];
            GG[t * 16 + h] = GG[t * 16 + h] / run;                 // sigmoid/denom
        }
    }
    __syncthreads();

    // wkv: [256 t] x [192 s] @ [192 s][16 c]; A-frags from global w2t (L2-hot)
    f32x4 wa[4];
    #pragma unroll
    for (int mi = 0; mi < 4; ++mi) wa[mi] = (f32x4){0.f,0.f,0.f,0.f};
    #pragma unroll
    for (int s0 = 0; s0 < SP; s0 += 32) {
        int scol = s0 + (q << 3);
        u32 boff = ((u32)(hs * 384 + scol * 2)) ^ (((u32)(hs & 7)) << 4);
        bf16x8 bfr = *(const bf16x8*)(smem + SKVT + boff);
        #pragma unroll
        for (int mi = 0; mi < 4; ++mi) {
            int row = (wid + (mi << 2)) * 16 + hs;
            bf16x8 afr = *(const bf16x8*)(w2t + row * SP + scol);
            wa[mi] = __builtin_amdgcn_mfma_f32_16x16x32_bf16(afr, bfr, wa[mi], 0,0,0);
        }
    }
    #pragma unroll
    for (int mi = 0; mi < 4; ++mi) {
        int tb = (wid + (mi << 2)) * 16 + (q << 2);
        #pragma unroll
        for (int rg = 0; rg < 4; ++rg) {
            int t = tb + rg;
            float fac = (t < S_LEN) ? GG[t * 16 + hs] : 0.5f;
            ((__bf16*)(smem + SRB))[t * 40 + hs] = (__bf16)(wa[mi][rg] * fac);
        }
    }
    __syncthreads();

    float obv[4];
    #pragma unroll
    for (int nt = 0; nt < 4; ++nt) obv[nt] = out_b[nt * 16 + hs];
    #pragma unroll
    for (int mi = 0; mi < 4; ++mi) {
        int mt = wid + (mi << 2);
        int arow = mt * 16 + hs;
        bf16x8 afr = *(const bf16x8*)(smem + SRB + (u32)(arow * 80 + (q << 4)));
        float gm[4];
        #pragma unroll
        for (int rg = 0; rg < 4; ++rg) gm[rg] = gamma[mt * 16 + (q << 2) + rg];
        #pragma unroll
        for (int nt = 0; nt < 4; ++nt) {
            int orow = nt * 16 + hs;
            bf16x8 bfr = *(const bf16x8*)(smem + SOW + (u32)(orow * 80 + (q << 4)));
            f32x4 zc = (f32x4){0.f,0.f,0.f,0.f};
            f32x4 d = __builtin_amdgcn_mfma_f32_16x16x32_bf16(afr, bfr, zc, 0,0,0);
            #pragma unroll
            for (int rg = 0; rg < 4; ++rg) {
                int t = mt * 16 + (q << 2) + rg;
                out[(size_t)b * 16384 + (size_t)t * 64 + nt * 16 + hs] = (d[rg] + obv[nt]) * gm[rg];
            }
        }
    }
}

extern "C" void kernel_launch(void* const* d_in, const int* in_sizes, int n_in,
                              void* d_out, int out_size, void* d_ws, size_t ws_size,
                              hipStream_t stream) {
    const float* x          = (const float*)d_in[0];
    const float* time_w     = (const float*)d_in[1];
    const float* time_alpha = (const float*)d_in[2];
    const float* time_beta  = (const float*)d_in[3];
    const float* time_gamma = (const float*)d_in[4];
    const float* key_w      = (const float*)d_in[5];
    const float* key_b      = (const float*)d_in[6];
    const float* value_w    = (const float*)d_in[7];
    const float* value_b    = (const float*)d_in[8];
    const float* recep_w    = (const float*)d_in[9];
    const float* recep_b    = (const float*)d_in[10];
    const float* out_w      = (const float*)d_in[11];
    const float* out_b      = (const float*)d_in[12];
    char* ws = (char*)d_ws;

    k0_kernel<<<195, 1024, 0, stream>>>(time_w, time_alpha, time_beta,
                                        key_w, value_w, recep_w, ws);
    g_kernel<<<2816, 192, 0, stream>>>(x, key_b, value_b, recep_b, ws);
    scan_kernel<<<256, 256, 0, stream>>>(ws, out_w, out_b, time_gamma, (float*)d_out);
}

// Round 10
// 40.746 us; speedup vs baseline: 2.4043x; 1.0280x over previous
//
#include <hip/hip_runtime.h>

typedef unsigned short u16;
typedef unsigned int u32;
typedef __attribute__((ext_vector_type(8))) __bf16 bf16x8;
typedef __attribute__((ext_vector_type(4))) __bf16 bf16x4;
typedef __attribute__((ext_vector_type(4))) float f32x4;

#define S_LEN 169
#define SP 192

// ---------------- workspace layout (bytes)
// w2a: w2^T in MFMA A-frag layout: frag(rt,ks) 1KB blocks, rt=t>>4 (16), ks=s>>5 (6)
//      element (t,s): addr = ((rt*6+ks)*64 + ((s>>3)&3)*16 + (t&15))*16 + (s&7)*2
#define W2A_WS 0                          // 98304
#define WPK_WS 98304                      // bf16 frag-packed weights [3][1024][16B] = 49152
#define KE_WS  147456                     // bf16 [256][176][16] = 1441792
#define KV_WS  (KE_WS + 1441792)
#define SG_WS  (KV_WS + 1441792)

// ---------------- S kernel LDS
#define SKE  0        // bf16 [176][16]
#define SKV  5632     // bf16 [176][16]
#define SG2  11264    // bf16 [176][16] (sigmoid r)
#define DEN  16896    // f32  [176][16] (1/cumsum)
#define SKVT 28160    // bf16 [16][192] swz
#define SRB  34304    // bf16 [256][40]
#define SSS  54784    // f32  [16][16]
#define SOW  55808    // bf16 [64][40]
#define S_LDS 60928

// ---------------- K0: blocks 0..191 compute w2a (frag layout); 192..194 pack weights
__global__ __launch_bounds__(1024) void k0_kernel(
    const float* __restrict__ time_w,
    const float* __restrict__ time_alpha,
    const float* __restrict__ time_beta,
    const float* __restrict__ key_w,
    const float* __restrict__ value_w,
    const float* __restrict__ recep_w,
    char* __restrict__ ws)
{
    const int blk = blockIdx.x;
    if (blk >= 192) {
        const int m = blk - 192;
        const float* wmat = (m == 0) ? key_w : (m == 1) ? value_w : recep_w;
        const int g = threadIdx.x;   // 1024 granules of 8 f32, coalesced
        const float* src = wmat + g * 8;
        float4 f0 = *(const float4*)src;
        float4 f1 = *(const float4*)(src + 4);
        bf16x8 p;
        p[0]=(__bf16)f0.x; p[1]=(__bf16)f0.y; p[2]=(__bf16)f0.z; p[3]=(__bf16)f0.w;
        p[4]=(__bf16)f1.x; p[5]=(__bf16)f1.y; p[6]=(__bf16)f1.z; p[7]=(__bf16)f1.w;
        int hs = g >> 6, rem = g & 63, ks = rem >> 2, q = rem & 3;
        int fid = ks * 64 + q * 16 + hs;
        *(bf16x8*)(ws + WPK_WS + m * 16384 + fid * 16) = p;
        return;
    }
    __shared__ float tw[256];
    __shared__ float al[256];
    __shared__ float part[4][256];
    const int s = blk;
    const int t = threadIdx.x & 255;
    const int p = threadIdx.x >> 8;
    const u32 adr = (u32)((( (t >> 4) * 6 + (s >> 5)) * 64 + ((s >> 3) & 3) * 16 + (t & 15)) * 16
                          + (s & 7) * 2);
    if (s >= S_LEN) {                      // zero-pad s in [169,192)
        if (p == 0) *(u16*)(ws + W2A_WS + adr) = 0;
        return;
    }
    if (p == 0) { tw[t] = time_w[s * 256 + t]; al[t] = time_alpha[s * 256 + t]; }
    __syncthreads();
    const int u0 = p << 6;
    const int u1 = (u0 + 64 < t + 1) ? (u0 + 64) : (t + 1);
    float acc = 0.f;
    for (int u = u0; u < u1; ++u)
        acc = fmaf(tw[255 + u - t], al[u], acc);
    part[p][t] = acc;
    __syncthreads();
    if (p == 0) {
        __bf16 v = (__bf16)(time_beta[s * 256 + t] *
                            (part[0][t] + part[1][t] + part[2][t] + part[3][t]));
        *(u16*)(ws + W2A_WS + adr) = *(u16*)&v;
    }
}

// ---------------- G: GEMM1 + pointwise. 2816 blocks = (b, slab of 16 t-rows), 192 thr.
// One-shot: contiguous stage -> 1 barrier -> 16 MFMA/wave -> epilogue (bf16 ws writes).
__global__ __launch_bounds__(192) void g_kernel(
    const float* __restrict__ x,
    const float* __restrict__ key_b,
    const float* __restrict__ value_b,
    const float* __restrict__ recep_b,
    char* __restrict__ ws)
{
    __shared__ __align__(16) char smem[17408];   // bf16 [17][512] swizzled
    const int tid  = threadIdx.x;
    const int lane = tid & 63;
    const int wid  = tid >> 6;       // 0..2 -> matrices k/v/r
    const int q    = lane >> 4;
    const int hs   = lane & 15;
    const int blk  = blockIdx.x;
    const int b    = blk / 11;
    const int slab = blk - b * 11;
    const int t0   = slab * 16;
    const float* xb = x + (size_t)b * (S_LEN * 512);

    // B-fragments from pre-packed ws (k0 output, L2-hot): 16 contiguous 1 KB wave-loads
    bf16x8 bfrag[16];
    #pragma unroll
    for (int ks = 0; ks < 16; ++ks)
        bfrag[ks] = *(const bf16x8*)(ws + WPK_WS + wid * 16384 + (ks * 64 + lane) * 16);
    const float* bv = (wid == 0) ? key_b : (wid == 1) ? value_b : recep_b;
    const float bias = bv[hs];

    // stage rows t0-1 .. t0+15 (17 rows x 512 f32 = one contiguous 34 KB sweep)
    float4 st[12];
    int    sv[12];
    #pragma unroll
    for (int it = 0; it < 12; ++it) {
        int idx = tid + it * 192; if (idx > 2175) idx = 2175;   // 17*128 float4s
        int row = idx >> 7, c4 = idx & 127;
        int g   = t0 - 1 + row;
        sv[it]  = ((unsigned)g < (unsigned)S_LEN) ? 1 : 0;
        int gc  = g < 0 ? 0 : (g > S_LEN - 1 ? S_LEN - 1 : g);
        st[it]  = *(const float4*)(xb + (size_t)gc * 512 + c4 * 4);
    }
    #pragma unroll
    for (int it = 0; it < 12; ++it) {
        int idx = tid + it * 192; if (idx > 2175) idx = 2175;
        int row = idx >> 7, c4 = idx & 127;
        float4 f = st[it];
        if (!sv[it]) f = (float4){0.f, 0.f, 0.f, 0.f};
        bf16x4 p;
        p[0] = (__bf16)f.x; p[1] = (__bf16)f.y; p[2] = (__bf16)f.z; p[3] = (__bf16)f.w;
        u32 off = (u32)row * 1024 + ((((u32)c4) * 8u) ^ (((u32)(row & 7)) << 4));
        *(bf16x4*)(smem + off) = p;
    }
    __syncthreads();

    // MFMA: A[t0+hs][k] from LDS (shift rows: ks<8 -> staged row hs, else hs+1)
    f32x4 acc = (f32x4){0.f, 0.f, 0.f, 0.f};
    #pragma unroll
    for (int ks = 0; ks < 16; ++ks) {
        int r = hs + ((ks < 8) ? 0 : 1);
        u32 off = (u32)r * 1024 + (((u32)(ks * 64 + q * 16)) ^ (((u32)(r & 7)) << 4));
        bf16x8 a = *(const bf16x8*)(smem + off);
        acc = __builtin_amdgcn_mfma_f32_16x16x32_bf16(a, bfrag[ks], acc, 0, 0, 0);
    }
    __syncthreads();   // staging reads done; reuse LDS for raw exchange

    // epilogue: raw (+bias) -> LDS [3][16][16] f32, barrier, combine -> ws (bf16)
    float* raw = (float*)smem;
    #pragma unroll
    for (int rg = 0; rg < 4; ++rg)
        raw[wid * 256 + (q * 4 + rg) * 16 + hs] = acc[rg] + bias;
    __syncthreads();

    __bf16* keg = (__bf16*)(ws + KE_WS);
    __bf16* kvg = (__bf16*)(ws + KV_WS);
    __bf16* sgg = (__bf16*)(ws + SG_WS);
    for (int i = tid; i < 256; i += 192) {
        int tl = i >> 4, h = i & 15;
        int t  = t0 + tl;
        if (t < S_LEN) {
            float kk = fminf(fmaxf(raw[i], -60.f), 30.f);
            float ke = __expf(kk);
            size_t o = ((size_t)b * 176 + t) * 16 + h;
            keg[o] = (__bf16)ke;
            kvg[o] = (__bf16)(ke * raw[256 + i]);
            sgg[o] = (__bf16)(1.f / (1.f + __expf(-raw[512 + i])));
        }
    }
}

// ---------------- kernel S: scan + wkv + out-proj. 256 blocks (one per b)
__global__ __launch_bounds__(256) void scan_kernel(
    const char* __restrict__ wsr,
    const float* __restrict__ out_w, const float* __restrict__ out_b,
    const float* __restrict__ gamma,
    float* __restrict__ out)
{
    __shared__ __align__(16) char smem[S_LDS];
    const int tid  = threadIdx.x;
    const int lane = tid & 63;
    const int wid  = tid >> 6;
    const int q    = lane >> 4;
    const int hs   = lane & 15;
    const int b    = blockIdx.x;
    const float4* keb = (const float4*)(wsr + KE_WS + (size_t)b * 5632);
    const float4* kvb = (const float4*)(wsr + KV_WS + (size_t)b * 5632);
    const float4* sgb = (const float4*)(wsr + SG_WS + (size_t)b * 5632);

    // coop loads: ke, kv, sigmoid (bf16, 338 float4 each)
    #pragma unroll
    for (int it = 0; it < 2; ++it) {
        int i = tid + (it << 8);
        if (i < 338) {
            ((float4*)(smem + SKE))[i] = keb[i];
            ((float4*)(smem + SKV))[i] = kvb[i];
            ((float4*)(smem + SG2))[i] = sgb[i];
        }
    }
    for (int i = tid; i < 2560; i += 256) {
        int o = i / 40, c = i - o * 40;
        ((__bf16*)(smem + SOW))[i] = (c < 16) ? (__bf16)out_w[o * 16 + c] : (__bf16)0.f;
    }
    for (int i = tid; i < 4096; i += 256) {
        int row = i >> 4, c = 16 + (i & 15);
        ((__bf16*)(smem + SRB))[row * 40 + c] = (__bf16)0.f;
    }
    for (int i = tid; i < 368; i += 256) {
        int h2 = i & 15; int t = S_LEN + (i >> 4);
        u32 off = ((u32)(h2 * 384 + t * 2)) ^ (((u32)(h2 & 7)) << 4);
        *(__bf16*)(smem + SKVT + off) = (__bf16)0.f;
    }
    __syncthreads();

    const __bf16* KE = (const __bf16*)(smem + SKE);
    const __bf16* SGb = (const __bf16*)(smem + SG2);
    float* DENi = (float*)(smem + DEN);
    float* SEG = (float*)(smem + SSS);
    const int h  = tid & 15;
    const int sg = tid >> 4;
    const int ts = sg * 11;
    const int te = (ts + 11 < S_LEN) ? ts + 11 : S_LEN;
    {
        float ssum = 0.f;
        for (int t = ts; t < te; ++t) ssum += (float)KE[t * 16 + h];
        SEG[sg * 16 + h] = ssum;
    }
    __syncthreads();
    {
        float run = 0.f;
        for (int s2 = 0; s2 < sg; ++s2) run += SEG[s2 * 16 + h];   // broadcast reads
        for (int t = ts; t < te; ++t) {
            run += (float)KE[t * 16 + h];                          // inclusive cumsum
            DENi[t * 16 + h] = 1.f / run;
            u32 off = ((u32)(h * 384 + t * 2)) ^ (((u32)(h & 7)) << 4);
            *(u16*)(smem + SKVT + off) = ((const u16*)(smem + SKV))[t * 16 + h];
        }
    }
    __syncthreads();

    // wkv: A-frags from w2a (frag layout, coalesced, L2-hot) x kvT (LDS)
    f32x4 wa[4];
    #pragma unroll
    for (int mi = 0; mi < 4; ++mi) wa[mi] = (f32x4){0.f,0.f,0.f,0.f};
    #pragma unroll
    for (int ks = 0; ks < 6; ++ks) {
        int scol = ks * 32 + (q << 3);
        u32 boff = ((u32)(hs * 384 + scol * 2)) ^ (((u32)(hs & 7)) << 4);
        bf16x8 bfr = *(const bf16x8*)(smem + SKVT + boff);
        #pragma unroll
        for (int mi = 0; mi < 4; ++mi) {
            int rt = wid + (mi << 2);
            bf16x8 afr = *(const bf16x8*)(wsr + W2A_WS + (u32)(((rt * 6 + ks) * 64 + lane) * 16));
            wa[mi] = __builtin_amdgcn_mfma_f32_16x16x32_bf16(afr, bfr, wa[mi], 0,0,0);
        }
    }
    #pragma unroll
    for (int mi = 0; mi < 4; ++mi) {
        int tb = (wid + (mi << 2)) * 16 + (q << 2);
        #pragma unroll
        for (int rg = 0; rg < 4; ++rg) {
            int t = tb + rg;
            float fac = (t < S_LEN) ? (float)SGb[t * 16 + hs] * DENi[t * 16 + hs] : 0.5f;
            ((__bf16*)(smem + SRB))[t * 40 + hs] = (__bf16)(wa[mi][rg] * fac);
        }
    }
    __syncthreads();

    float obv[4];
    #pragma unroll
    for (int nt = 0; nt < 4; ++nt) obv[nt] = out_b[nt * 16 + hs];
    #pragma unroll
    for (int mi = 0; mi < 4; ++mi) {
        int mt = wid + (mi << 2);
        int arow = mt * 16 + hs;
        bf16x8 afr = *(const bf16x8*)(smem + SRB + (u32)(arow * 80 + (q << 4)));
        float gm[4];
        #pragma unroll
        for (int rg = 0; rg < 4; ++rg) gm[rg] = gamma[mt * 16 + (q << 2) + rg];
        #pragma unroll
        for (int nt = 0; nt < 4; ++nt) {
            int orow = nt * 16 + hs;
            bf16x8 bfr = *(const bf16x8*)(smem + SOW + (u32)(orow * 80 + (q << 4)));
            f32x4 zc = (f32x4){0.f,0.f,0.f,0.f};
            f32x4 d = __builtin_amdgcn_mfma_f32_16x16x32_bf16(afr, bfr, zc, 0,0,0);
            #pragma unroll
            for (int rg = 0; rg < 4; ++rg) {
                int t = mt * 16 + (q << 2) + rg;
                out[(size_t)b * 16384 + (size_t)t * 64 + nt * 16 + hs] = (d[rg] + obv[nt]) * gm[rg];
            }
        }
    }
}

extern "C" void kernel_launch(void* const* d_in, const int* in_sizes, int n_in,
                              void* d_out, int out_size, void* d_ws, size_t ws_size,
                              hipStream_t stream) {
    const float* x          = (const float*)d_in[0];
    const float* time_w     = (const float*)d_in[1];
    const float* time_alpha = (const float*)d_in[2];
    const float* time_beta  = (const float*)d_in[3];
    const float* time_gamma = (const float*)d_in[4];
    const float* key_w      = (const float*)d_in[5];
    const float* key_b      = (const float*)d_in[6];
    const float* value_w    = (const float*)d_in[7];
    const float* value_b    = (const float*)d_in[8];
    const float* recep_w    = (const float*)d_in[9];
    const float* recep_b    = (const float*)d_in[10];
    const float* out_w      = (const float*)d_in[11];
    const float* out_b      = (const float*)d_in[12];
    char* ws = (char*)d_ws;

    k0_kernel<<<195, 1024, 0, stream>>>(time_w, time_alpha, time_beta,
                                        key_w, value_w, recep_w, ws);
    g_kernel<<<2816, 192, 0, stream>>>(x, key_b, value_b, recep_b, ws);
    scan_kernel<<<256, 256, 0, stream>>>(ws, out_w, out_b, time_gamma, (float*)d_out);
}